// Round 19
// baseline (409.868 us; speedup 1.0000x reference)
//
#include <hip/hip_runtime.h>
#include <hip/hip_bf16.h>
#include <math.h>

// Problem constants (from reference)
#define S_   512
#define B_   32
#define D_   256
#define H_   8
#define DH_  32
#define E_   (H_*(5*DH_+2))   // 1296
#define SB_  (S_*B_)          // 16384
#define LN_EPSF 1e-5f

#define ROWB_ 384             // compact row stride BYTES (324 used, 16B-aligned)
#define ROWS_ 192             // compact row stride in ushorts
#define NPAD_ 1344            // slow_W rows padded to 21*64 (zero-filled tail)

typedef short        bf16x8 __attribute__((ext_vector_type(8)));
typedef float        f32x4  __attribute__((ext_vector_type(4)));
typedef unsigned int u32x4  __attribute__((ext_vector_type(4)));

// ---------------- cross-lane helpers ----------------
__device__ __forceinline__ float wave_sum64(float v){
  #pragma unroll
  for (int m = 32; m >= 1; m >>= 1) v += __shfl_xor(v, m, 64);
  return v;
}
__device__ __forceinline__ float gsum32(float v){
  #pragma unroll
  for (int m = 16; m >= 1; m >>= 1) v += __shfl_xor(v, m, 32);
  return v;
}
__device__ __forceinline__ float gmax32(float v){
  #pragma unroll
  for (int m = 16; m >= 1; m >>= 1) v = fmaxf(v, __shfl_xor(v, m, 32));
  return v;
}

// cross-half (lane r <-> lane r+32) SUM via v_permlane32_swap_b32 (VALU).
#if __has_builtin(__builtin_amdgcn_permlane32_swap)
typedef int v2i_ __attribute__((ext_vector_type(2)));
__device__ __forceinline__ float xhalf_sum(float x){
  v2i_ r = __builtin_amdgcn_permlane32_swap(__float_as_int(x), __float_as_int(x), false, false);
  return __int_as_float(r.x) + __int_as_float(r.y);
}
#else
__device__ __forceinline__ float xhalf_sum(float x){
  return x + __shfl_xor(x, 32, 64);
}
#endif

// bf16 helpers
__device__ __forceinline__ float bfl(unsigned u){ return __int_as_float((int)(u << 16)); }
__device__ __forceinline__ float bfh(unsigned u){ return __int_as_float((int)(u & 0xffff0000u)); }
__device__ __forceinline__ unsigned short bfb(float f){
  __hip_bfloat16 h = __float2bfloat16(f); return *(unsigned short*)&h;
}
__device__ __forceinline__ float bf2f(unsigned short u){
  return __int_as_float(((int)u) << 16);
}

// ---- inline-asm global loads (SGPR base + VGPR byte-voffset + imm) ----
// PROVEN R10/R18 form (2-deep pipeline only — depth>2 failed 6x).
#define GL4(dst, sb, vo, IMM) \
  asm volatile("global_load_dwordx4 %0, %1, %2 offset:" IMM \
               : "=&v"(dst) : "v"(vo), "s"(sb))
#define GL1(dst, sb, vo, IMM) \
  asm volatile("global_load_dword %0, %1, %2 offset:" IMM \
               : "=&v"(dst) : "v"(vo), "s"(sb))

// ---------------- LayerNorm -> bf16 output ----------------
__global__ __launch_bounds__(256) void ln_kernel(const float* __restrict__ x,
                                                 const float* __restrict__ g,
                                                 const float* __restrict__ b,
                                                 __hip_bfloat16* __restrict__ o){
  __shared__ float sbuf[4];
  const int row = blockIdx.x, tid = threadIdx.x;
  const float v = x[(size_t)row*D_ + tid];
  float s = wave_sum64(v);
  if ((tid & 63) == 0) sbuf[tid >> 6] = s;
  __syncthreads();
  const float mu = (sbuf[0]+sbuf[1]+sbuf[2]+sbuf[3]) * (1.f/D_);
  __syncthreads();
  const float d = v - mu;
  float s2 = wave_sum64(d*d);
  if ((tid & 63) == 0) sbuf[tid >> 6] = s2;
  __syncthreads();
  const float var = (sbuf[0]+sbuf[1]+sbuf[2]+sbuf[3]) * (1.f/D_);
  const float rstd = rsqrtf(var + LN_EPSF);
  o[(size_t)row*D_ + tid] = __float2bfloat16(d*rstd*g[tid] + b[tid]);
}

// ---------------- weight conversions (merged: one launch) ----------------
__global__ __launch_bounds__(256) void cvt_w(const float* __restrict__ W1,
                                             const float* __restrict__ W2,
                                             __hip_bfloat16* __restrict__ o1,
                                             __hip_bfloat16* __restrict__ o2){
  const int r = blockIdx.x, c = threadIdx.x;
  if (r < NPAD_){
    const float v = (r < E_) ? W1[(size_t)r*D_ + c] : 0.f;
    o1[(size_t)r*D_ + c] = __float2bfloat16(v);
  } else {
    const int r2 = r - NPAD_;
    o2[(size_t)r2*D_ + c] = __float2bfloat16(W2[(size_t)r2*D_ + c]);
  }
}

// compact-row byte offset for head-local element jj (0..161)
__device__ __forceinline__ int cmp_off(int jj){
  if (jj < 64)  return 2*jj;
  if (jj < 96)  return 4*jj - 64;
  if (jj < 128) return 2*jj - 64;
  if (jj < 160) return 4*jj - 318;
  return 320 + 2*(jj - 160);
}

// ---------------- GEMM1 (MFMA bf16) -> COMPACT bf16 qkvT scatter ----------------
__global__ __launch_bounds__(256) void gemm1_mfma(const __hip_bfloat16* __restrict__ A,
                                                  const __hip_bfloat16* __restrict__ Bw,
                                                  unsigned short* __restrict__ qc){
  const int tid = threadIdx.x;
  const int w = tid >> 6, l = tid & 63;
  const int lr = l & 15, lk = (l >> 4) << 3;
  const int m0 = blockIdx.y*64 + (w>>1)*32;
  const int n0 = blockIdx.x*64 + (w&1)*32;

  const __hip_bfloat16* Ap = A  + (size_t)(m0+lr)*D_ + lk;
  const __hip_bfloat16* Bp = Bw + (size_t)(n0+lr)*D_ + lk;

  f32x4 acc00={0,0,0,0}, acc01={0,0,0,0}, acc10={0,0,0,0}, acc11={0,0,0,0};
  #pragma unroll
  for (int ks = 0; ks < 8; ++ks){
    const bf16x8 a0 = *(const bf16x8*)(Ap + ks*32);
    const bf16x8 a1 = *(const bf16x8*)(Ap + 16*D_ + ks*32);
    const bf16x8 b0 = *(const bf16x8*)(Bp + ks*32);
    const bf16x8 b1 = *(const bf16x8*)(Bp + 16*D_ + ks*32);
    acc00 = __builtin_amdgcn_mfma_f32_16x16x32_bf16(a0, b0, acc00, 0,0,0);
    acc01 = __builtin_amdgcn_mfma_f32_16x16x32_bf16(a0, b1, acc01, 0,0,0);
    acc10 = __builtin_amdgcn_mfma_f32_16x16x32_bf16(a1, b0, acc10, 0,0,0);
    acc11 = __builtin_amdgcn_mfma_f32_16x16x32_bf16(a1, b1, acc11, 0,0,0);
  }

  const int mrow = (l>>4)<<2;
  #pragma unroll
  for (int i=0;i<2;i++){
    #pragma unroll
    for (int j=0;j<2;j++){
      const f32x4 av = (i==0) ? (j==0?acc00:acc01) : (j==0?acc10:acc11);
      const int n = n0 + j*16 + lr;
      if (n < E_){
        const unsigned head = (unsigned)n / 162u;
        const int jj = n - (int)head*162;
        const int off = cmp_off(jj);
        #pragma unroll
        for (int reg=0;reg<4;reg++){
          const int m = m0 + i*16 + mrow + reg;
          const int s = m >> 5, bq = m & 31;
          char* rowb = (char*)qc + ((size_t)(bq*8u+head)*S_ + s)*ROWB_;
          *(unsigned short*)(rowb + off) = bfb(av[reg]);
        }
      }
    }
  }
}

// ---------------- GEMM2 (MFMA bf16): out = hs_bf . out_W^T + x ----------------
__global__ __launch_bounds__(256) void gemm2_mfma(const __hip_bfloat16* __restrict__ A,
                                                  const __hip_bfloat16* __restrict__ Bw,
                                                  const float* __restrict__ X,
                                                  float* __restrict__ C){
  const int tid = threadIdx.x;
  const int w = tid >> 6, l = tid & 63;
  const int lr = l & 15, lk = (l >> 4) << 3;
  const int m0 = blockIdx.y*64 + (w>>1)*32;
  const int n0 = blockIdx.x*64 + (w&1)*32;

  const __hip_bfloat16* Ap = A  + (size_t)(m0+lr)*D_ + lk;
  const __hip_bfloat16* Bp = Bw + (size_t)(n0+lr)*D_ + lk;

  f32x4 acc00={0,0,0,0}, acc01={0,0,0,0}, acc10={0,0,0,0}, acc11={0,0,0,0};
  #pragma unroll
  for (int ks = 0; ks < 8; ++ks){
    const bf16x8 a0 = *(const bf16x8*)(Ap + ks*32);
    const bf16x8 a1 = *(const bf16x8*)(Ap + 16*D_ + ks*32);
    const bf16x8 b0 = *(const bf16x8*)(Bp + ks*32);
    const bf16x8 b1 = *(const bf16x8*)(Bp + 16*D_ + ks*32);
    acc00 = __builtin_amdgcn_mfma_f32_16x16x32_bf16(a0, b0, acc00, 0,0,0);
    acc01 = __builtin_amdgcn_mfma_f32_16x16x32_bf16(a0, b1, acc01, 0,0,0);
    acc10 = __builtin_amdgcn_mfma_f32_16x16x32_bf16(a1, b0, acc10, 0,0,0);
    acc11 = __builtin_amdgcn_mfma_f32_16x16x32_bf16(a1, b1, acc11, 0,0,0);
  }

  const int mrow = (l>>4)<<2;
  #pragma unroll
  for (int i=0;i<2;i++){
    #pragma unroll
    for (int j=0;j<2;j++){
      const f32x4 av = (i==0) ? (j==0?acc00:acc01) : (j==0?acc10:acc11);
      const int n = n0 + j*16 + lr;
      #pragma unroll
      for (int reg=0;reg<4;reg++){
        const size_t m = (size_t)(m0 + i*16 + mrow + reg);
        C[m*D_ + n] = av[reg] + X[m*D_ + n];
      }
    }
  }
}

// ---------------- act4: activations in-place on COMPACT bf16 rows ----------------
__global__ __launch_bounds__(256) void act4_kernel(unsigned short* __restrict__ qc){
  const int row = blockIdx.x*8 + (threadIdx.x >> 5);
  const int i = threadIdx.x & 31;
  unsigned short* base = qc + (size_t)row*ROWS_;
  float qv  = bf2f(base[i]);
  float kv  = bf2f(base[32 + i]);
  float rkv = bf2f(base[64 + i]);
  qv = qv > 0.f ? qv + 1.f : __expf(qv);   // elu+1
  kv = kv > 0.f ? kv + 1.f : __expf(kv);
  const float qs = gsum32(qv);
  const float ks = gsum32(kv);
  const float rm = gmax32(rkv);
  const float re = __expf(rkv - rm);
  const float rs = gsum32(re);
  base[i]      = bfb(qv / qs);
  base[32 + i] = bfb(kv / ks);
  base[64 + i] = bfb(re / rs);
  if (i < 2){
    const float bv = bf2f(base[160 + i]);
    base[160 + i] = bfb(1.f/(1.f + __expf(-bv)));
  }
}

// ---------------- fused scan: 2-deep bf16 pipeline, h via LDS (store off vmcnt) ----------------
// R18-proven skeleton. KEY CHANGE (R19): the per-step h-store to HBM is
// REMOVED from the vmcnt stream — vmcnt retires IN ORDER, so every per-step
// wait was blocked by a 2-body-old HBM store (~2000cyc), which is why R18's
// load halving changed nothing. h now goes to an LDS buffer (lgkmcnt domain);
// a wave-wide bulk dump (4 dwordx4 stores) flushes each 64-step chunk,
// amortizing the store latency 64x. Steady wait = vmcnt(8) (pure loads).
#define SCAN_ISSUE(P, sbp)                                                    \
  { const char* sb_ = (sbp);                                                  \
    GL4(P##q0, sb_, voQ, "0");   GL4(P##q1, sb_, voQ, "16");                  \
    GL4(P##k0, sb_, voQ, "64");  GL4(P##k1, sb_, voQ, "80");                  \
    GL4(P##r0, sb_, voQ, "128"); GL4(P##r1, sb_, voQ, "144");                 \
    GL1(P##vr, sb_, voV, "192");                                              \
    GL1(P##bb, sb_, voZ, "320"); }

#define SCAN_BODY(P, tt)                                                      \
  {                                                                           \
    /* e-transpose into the DS pipe first (depends only on prev h) */         \
    const float e_ = __expf(h);                                               \
    ebuf[r] = e_;                                                             \
    f32x4 ev0 = *(const f32x4*)&ebuf[p16+0];                                  \
    f32x4 ev1 = *(const f32x4*)&ebuf[p16+4];                                  \
    f32x4 ev2 = *(const f32x4*)&ebuf[p16+8];                                  \
    f32x4 ev3 = *(const f32x4*)&ebuf[p16+12];                                 \
    /* wait for THIS step's input registers (loads only in the stream) */     \
    if ((tt) >= S_-2) { asm volatile("s_waitcnt vmcnt(0)" ::: "memory"); }    \
    else              { asm volatile("s_waitcnt vmcnt(8)" ::: "memory"); }    \
    __builtin_amdgcn_sched_barrier(0);                                        \
    /* unpack bf16 (1 VALU op per element) */                                 \
    float q_[16], k_[16], rk_[16];                                            \
    q_[0]=bfl(P##q0[0]);  q_[1]=bfh(P##q0[0]);  q_[2]=bfl(P##q0[1]);  q_[3]=bfh(P##q0[1]); \
    q_[4]=bfl(P##q0[2]);  q_[5]=bfh(P##q0[2]);  q_[6]=bfl(P##q0[3]);  q_[7]=bfh(P##q0[3]); \
    q_[8]=bfl(P##q1[0]);  q_[9]=bfh(P##q1[0]);  q_[10]=bfl(P##q1[1]); q_[11]=bfh(P##q1[1]);\
    q_[12]=bfl(P##q1[2]); q_[13]=bfh(P##q1[2]); q_[14]=bfl(P##q1[3]); q_[15]=bfh(P##q1[3]);\
    k_[0]=bfl(P##k0[0]);  k_[1]=bfh(P##k0[0]);  k_[2]=bfl(P##k0[1]);  k_[3]=bfh(P##k0[1]); \
    k_[4]=bfl(P##k0[2]);  k_[5]=bfh(P##k0[2]);  k_[6]=bfl(P##k0[3]);  k_[7]=bfh(P##k0[3]); \
    k_[8]=bfl(P##k1[0]);  k_[9]=bfh(P##k1[0]);  k_[10]=bfl(P##k1[1]); k_[11]=bfh(P##k1[1]);\
    k_[12]=bfl(P##k1[2]); k_[13]=bfh(P##k1[2]); k_[14]=bfl(P##k1[3]); k_[15]=bfh(P##k1[3]);\
    rk_[0]=bfl(P##r0[0]);  rk_[1]=bfh(P##r0[0]);  rk_[2]=bfl(P##r0[1]);  rk_[3]=bfh(P##r0[1]); \
    rk_[4]=bfl(P##r0[2]);  rk_[5]=bfh(P##r0[2]);  rk_[6]=bfl(P##r0[3]);  rk_[7]=bfh(P##r0[3]); \
    rk_[8]=bfl(P##r1[0]);  rk_[9]=bfh(P##r1[0]);  rk_[10]=bfl(P##r1[1]); rk_[11]=bfh(P##r1[1]);\
    rk_[12]=bfl(P##r1[2]); rk_[13]=bfh(P##r1[2]); rk_[14]=bfl(P##r1[3]); rk_[15]=bfh(P##r1[3]);\
    const float vv   = bfl(P##vr), rvv   = bfh(P##vr);                        \
    const float beta = bfl(P##bb), rbeta = bfh(P##bb);                        \
    /* ---- ff chain ---- */                                                  \
    float a0=0.f,a1=0.f,a2=0.f,a3=0.f;                                        \
    _Pragma("unroll")                                                         \
    for (int c4=0;c4<16;c4+=4){                                               \
      a0=fmaf(W[c4+0],k_[c4+0],a0); a1=fmaf(W[c4+1],k_[c4+1],a1);             \
      a2=fmaf(W[c4+2],k_[c4+2],a2); a3=fmaf(W[c4+3],k_[c4+3],a3);             \
    }                                                                         \
    const float dot1f = xhalf_sum((a0+a1)+(a2+a3));                           \
    const float coeff = beta*(vv - dot1f);                                    \
    float b0=0.f,b1=0.f,b2=0.f,b3=0.f;                                        \
    _Pragma("unroll")                                                         \
    for (int c4=0;c4<16;c4+=4){                                               \
      W[c4+0]=fmaf(coeff,k_[c4+0],W[c4+0]); b0=fmaf(W[c4+0],q_[c4+0],b0);     \
      W[c4+1]=fmaf(coeff,k_[c4+1],W[c4+1]); b1=fmaf(W[c4+1],q_[c4+1],b1);     \
      W[c4+2]=fmaf(coeff,k_[c4+2],W[c4+2]); b2=fmaf(W[c4+2],q_[c4+2],b2);     \
      W[c4+3]=fmaf(coeff,k_[c4+3],W[c4+3]); b3=fmaf(W[c4+3],q_[c4+3],b3);     \
    }                                                                         \
    const float z_ = xhalf_sum((b0+b1)+(b2+b3));                              \
    /* ---- rec R delta update (h-independent) ---- */                        \
    float c0=0.f,c1=0.f,c2=0.f,c3=0.f;                                        \
    _Pragma("unroll")                                                         \
    for (int c4=0;c4<16;c4+=4){                                               \
      c0=fmaf(R[c4+0],rk_[c4+0],c0); c1=fmaf(R[c4+1],rk_[c4+1],c1);           \
      c2=fmaf(R[c4+2],rk_[c4+2],c2); c3=fmaf(R[c4+3],rk_[c4+3],c3);           \
    }                                                                         \
    const float dot1r = xhalf_sum((c0+c1)+(c2+c3));                           \
    const float coefr = rbeta*(rvv - dot1r);                                  \
    _Pragma("unroll")                                                         \
    for (int c4=0;c4<16;c4+=4){                                               \
      R[c4+0]=fmaf(coefr,rk_[c4+0],R[c4+0]); R[c4+1]=fmaf(coefr,rk_[c4+1],R[c4+1]); \
      R[c4+2]=fmaf(coefr,rk_[c4+2],R[c4+2]); R[c4+3]=fmaf(coefr,rk_[c4+3],R[c4+3]); \
    }                                                                         \
    /* ---- softmax-dot from the transposed e (read issued long ago) ---- */  \
    float evv[16];                                                            \
    *(f32x4*)&evv[0]=ev0; *(f32x4*)&evv[4]=ev1;                               \
    *(f32x4*)&evv[8]=ev2; *(f32x4*)&evv[12]=ev3;                              \
    float t0=(evv[0]+evv[1])+(evv[2]+evv[3]),   t1=(evv[4]+evv[5])+(evv[6]+evv[7]); \
    float t2=(evv[8]+evv[9])+(evv[10]+evv[11]), t3=(evv[12]+evv[13])+(evv[14]+evv[15]); \
    const float Ss = xhalf_sum((t0+t1)+(t2+t3));                              \
    float d0=0.f,d1=0.f,d2=0.f,d3=0.f;                                        \
    _Pragma("unroll")                                                         \
    for (int c4=0;c4<16;c4+=4){                                               \
      d0=fmaf(R[c4+0],evv[c4+0],d0); d1=fmaf(R[c4+1],evv[c4+1],d1);           \
      d2=fmaf(R[c4+2],evv[c4+2],d2); d3=fmaf(R[c4+3],evv[c4+3],d3);           \
    }                                                                         \
    const float dot2 = xhalf_sum((d0+d1)+(d2+d3));                            \
    h = fmaf(dot2, __builtin_amdgcn_rcpf(Ss), z_);                            \
    if (!p) hbuf[(tt)&63][r] = h;      /* DS write: lgkmcnt domain, NOT vmcnt */ \
    /* reissue this buffer for step tt+2 */                                   \
    if ((tt)+2 < S_) SCAN_ISSUE(P, gbase + (size_t)((tt)+2)*ROWB_);           \
  }

// bulk dump of chunk c (steps c*64 .. c*64+63): lane L handles step c*64+L.
#define SCAN_DUMP(c)                                                          \
  {                                                                           \
    float hv[32];                                                             \
    _Pragma("unroll")                                                         \
    for (int j=0;j<8;j++) *(f32x4*)&hv[4*j] = *(const f32x4*)&hbuf[lane][4*j];\
    unsigned pk[16];                                                          \
    _Pragma("unroll")                                                         \
    for (int i=0;i<16;i++)                                                    \
      pk[i] = (unsigned)bfb(hv[2*i]) | ((unsigned)bfb(hv[2*i+1]) << 16);      \
    u32x4* dst = (u32x4*)((char*)hsb                                          \
                 + ((size_t)(c)*64 + lane)*(size_t)(B_*D_*2)                  \
                 + (size_t)(b*D_ + hh*DH_)*2);                                \
    dst[0] = *(u32x4*)&pk[0];  dst[1] = *(u32x4*)&pk[4];                      \
    dst[2] = *(u32x4*)&pk[8];  dst[3] = *(u32x4*)&pk[12];                     \
  }

__global__ __launch_bounds__(64,1) void scan_fused2(const unsigned short* __restrict__ qc,
                                                    __hip_bfloat16* __restrict__ hsb){
  const int pair = blockIdx.x;
  const int lane = threadIdx.x;
  const int r = lane & 31, p = lane >> 5;
  const int p16 = p*16;
  const int b = pair >> 3, hh = pair & 7;
  const char* gbase = (const char*)qc + (size_t)pair*S_*ROWB_;

  __shared__ __align__(16) float ebuf[DH_];
  __shared__ __align__(16) float hbuf[64][36];   // 64 steps x 32 h (rows 144B, 16B-aligned)

  const int voQ = p*32;   // byte voffset for q/k/rk 16-col bf16 slices
  const int voV = r*4;    // byte voffset for the (v,rv) bf16 pair (base 192 in imm)
  const int voZ = 0;      // (beta,rbeta) row-uniform

  float W[16], R[16];
  #pragma unroll
  for (int i=0;i<16;i++){ W[i]=0.f; R[i]=0.f; }
  float h = 0.f;

  // 2-deep register buffer sets A (even steps) / B (odd steps)
  u32x4 Aq0,Aq1, Ak0,Ak1, Ar0,Ar1; unsigned Avr, Abb;
  u32x4 Bq0,Bq1, Bk0,Bk1, Br0,Br1; unsigned Bvr, Bbb;

  SCAN_ISSUE(A, gbase);                 // step 0
  SCAN_ISSUE(B, gbase + ROWB_);         // step 1
  asm volatile("s_waitcnt vmcnt(8)" ::: "memory");   // step-0 regs ready (B's 8 newer)
  __builtin_amdgcn_sched_barrier(0);

  for (int tc = 0; tc < S_; tc += 2){
    SCAN_BODY(A, tc);
    SCAN_BODY(B, tc+1);
    if ((tc & 63) == 62) SCAN_DUMP(tc >> 6);   // chunk complete -> bulk store
  }
}

// ---------------- launcher ----------------
extern "C" void kernel_launch(void* const* d_in, const int* in_sizes, int n_in,
                              void* d_out, int out_size, void* d_ws, size_t ws_size,
                              hipStream_t stream) {
  const float* x      = (const float*)d_in[0];
  const float* slow_W = (const float*)d_in[1];
  const float* out_W  = (const float*)d_in[2];
  const float* ln_g   = (const float*)d_in[3];
  const float* ln_b   = (const float*)d_in[4];
  float* out = (float*)d_out;

  // ws layout: qc (compact bf16) 50.3MB | obf/hsb (overlaid) 8.4MB | w1 | w2
  unsigned short* qc  = (unsigned short*)d_ws;                  // [256][512][192 ushorts]
  __hip_bfloat16* obf = (__hip_bfloat16*)((char*)d_ws + (size_t)B_*H_*S_*ROWB_);
  __hip_bfloat16* hsb = obf;                                    // overlay: obf dead after gemm1
  __hip_bfloat16* w1bf = obf + (size_t)SB_*D_;                  // [1344][256]
  __hip_bfloat16* w2bf = w1bf + (size_t)NPAD_*D_;               // [256][256]

  cvt_w<<<NPAD_ + D_, 256, 0, stream>>>(slow_W, out_W, w1bf, w2bf);
  ln_kernel<<<SB_, 256, 0, stream>>>(x, ln_g, ln_b, obf);

  dim3 g1(NPAD_/64, SB_/64);                   // (21, 256)
  gemm1_mfma<<<g1, 256, 0, stream>>>(obf, w1bf, qc);

  act4_kernel<<<B_*H_*S_/8, 256, 0, stream>>>(qc);

  scan_fused2<<<B_*H_, 64, 0, stream>>>(qc, hsb);

  dim3 g2(D_/64, SB_/64);                      // (4, 256)
  gemm2_mfma<<<g2, 256, 0, stream>>>(hsb, w2bf, x, out);
}

// Round 22
// 367.346 us; speedup vs baseline: 1.1158x; 1.1158x over previous
//
#include <hip/hip_runtime.h>
#include <hip/hip_bf16.h>
#include <math.h>

// Problem constants (from reference)
#define S_   512
#define B_   32
#define D_   256
#define H_   8
#define DH_  32
#define E_   (H_*(5*DH_+2))   // 1296
#define SB_  (S_*B_)          // 16384
#define LN_EPSF 1e-5f

#define ROWB_ 384             // compact row stride BYTES (324 used, 16B-aligned)
#define ROWS_ 192             // compact row stride in ushorts
#define NPAD_ 1344            // slow_W rows padded to 21*64 (zero-filled tail)

typedef short        bf16x8 __attribute__((ext_vector_type(8)));
typedef float        f32x4  __attribute__((ext_vector_type(4)));
typedef unsigned int u32x4  __attribute__((ext_vector_type(4)));

// ---------------- cross-lane helpers ----------------
__device__ __forceinline__ float wave_sum64(float v){
  #pragma unroll
  for (int m = 32; m >= 1; m >>= 1) v += __shfl_xor(v, m, 64);
  return v;
}
__device__ __forceinline__ float gsum32(float v){
  #pragma unroll
  for (int m = 16; m >= 1; m >>= 1) v += __shfl_xor(v, m, 32);
  return v;
}
__device__ __forceinline__ float gmax32(float v){
  #pragma unroll
  for (int m = 16; m >= 1; m >>= 1) v = fmaxf(v, __shfl_xor(v, m, 32));
  return v;
}

// cross-half (lane r <-> lane r+32) SUM via v_permlane32_swap_b32 (VALU).
#if __has_builtin(__builtin_amdgcn_permlane32_swap)
typedef int v2i_ __attribute__((ext_vector_type(2)));
__device__ __forceinline__ float xhalf_sum(float x){
  v2i_ r = __builtin_amdgcn_permlane32_swap(__float_as_int(x), __float_as_int(x), false, false);
  return __int_as_float(r.x) + __int_as_float(r.y);
}
#else
__device__ __forceinline__ float xhalf_sum(float x){
  return x + __shfl_xor(x, 32, 64);
}
#endif

// bf16 helpers
__device__ __forceinline__ float bfl(unsigned u){ return __int_as_float((int)(u << 16)); }
__device__ __forceinline__ float bfh(unsigned u){ return __int_as_float((int)(u & 0xffff0000u)); }
__device__ __forceinline__ unsigned short bfb(float f){
  __hip_bfloat16 h = __float2bfloat16(f); return *(unsigned short*)&h;
}
__device__ __forceinline__ float bf2f(unsigned short u){
  return __int_as_float(((int)u) << 16);
}

// ---- inline-asm global loads (SGPR base + VGPR byte-voffset + imm) ----
// PROVEN R10/R18 form (2-deep pipeline only — every variation failed 8x:
// depth 3/4, group-batching, early-reissue. DO NOT alter this structure).
#define GL4(dst, sb, vo, IMM) \
  asm volatile("global_load_dwordx4 %0, %1, %2 offset:" IMM \
               : "=&v"(dst) : "v"(vo), "s"(sb))
#define GL1(dst, sb, vo, IMM) \
  asm volatile("global_load_dword %0, %1, %2 offset:" IMM \
               : "=&v"(dst) : "v"(vo), "s"(sb))

// ---------------- LayerNorm -> bf16 output ----------------
__global__ __launch_bounds__(256) void ln_kernel(const float* __restrict__ x,
                                                 const float* __restrict__ g,
                                                 const float* __restrict__ b,
                                                 __hip_bfloat16* __restrict__ o){
  __shared__ float sbuf[4];
  const int row = blockIdx.x, tid = threadIdx.x;
  const float v = x[(size_t)row*D_ + tid];
  float s = wave_sum64(v);
  if ((tid & 63) == 0) sbuf[tid >> 6] = s;
  __syncthreads();
  const float mu = (sbuf[0]+sbuf[1]+sbuf[2]+sbuf[3]) * (1.f/D_);
  __syncthreads();
  const float d = v - mu;
  float s2 = wave_sum64(d*d);
  if ((tid & 63) == 0) sbuf[tid >> 6] = s2;
  __syncthreads();
  const float var = (sbuf[0]+sbuf[1]+sbuf[2]+sbuf[3]) * (1.f/D_);
  const float rstd = rsqrtf(var + LN_EPSF);
  o[(size_t)row*D_ + tid] = __float2bfloat16(d*rstd*g[tid] + b[tid]);
}

// ---------------- weight conversions (merged: one launch) ----------------
__global__ __launch_bounds__(256) void cvt_w(const float* __restrict__ W1,
                                             const float* __restrict__ W2,
                                             __hip_bfloat16* __restrict__ o1,
                                             __hip_bfloat16* __restrict__ o2){
  const int r = blockIdx.x, c = threadIdx.x;
  if (r < NPAD_){
    const float v = (r < E_) ? W1[(size_t)r*D_ + c] : 0.f;
    o1[(size_t)r*D_ + c] = __float2bfloat16(v);
  } else {
    const int r2 = r - NPAD_;
    o2[(size_t)r2*D_ + c] = __float2bfloat16(W2[(size_t)r2*D_ + c]);
  }
}

// compact-row byte offset for head-local element jj (0..161)
__device__ __forceinline__ int cmp_off(int jj){
  if (jj < 64)  return 2*jj;
  if (jj < 96)  return 4*jj - 64;
  if (jj < 128) return 2*jj - 64;
  if (jj < 160) return 4*jj - 318;
  return 320 + 2*(jj - 160);
}

// ---------------- GEMM1 (MFMA bf16) -> COMPACT bf16 qkvT scatter ----------------
__global__ __launch_bounds__(256) void gemm1_mfma(const __hip_bfloat16* __restrict__ A,
                                                  const __hip_bfloat16* __restrict__ Bw,
                                                  unsigned short* __restrict__ qc){
  const int tid = threadIdx.x;
  const int w = tid >> 6, l = tid & 63;
  const int lr = l & 15, lk = (l >> 4) << 3;
  const int m0 = blockIdx.y*64 + (w>>1)*32;
  const int n0 = blockIdx.x*64 + (w&1)*32;

  const __hip_bfloat16* Ap = A  + (size_t)(m0+lr)*D_ + lk;
  const __hip_bfloat16* Bp = Bw + (size_t)(n0+lr)*D_ + lk;

  f32x4 acc00={0,0,0,0}, acc01={0,0,0,0}, acc10={0,0,0,0}, acc11={0,0,0,0};
  #pragma unroll
  for (int ks = 0; ks < 8; ++ks){
    const bf16x8 a0 = *(const bf16x8*)(Ap + ks*32);
    const bf16x8 a1 = *(const bf16x8*)(Ap + 16*D_ + ks*32);
    const bf16x8 b0 = *(const bf16x8*)(Bp + ks*32);
    const bf16x8 b1 = *(const bf16x8*)(Bp + 16*D_ + ks*32);
    acc00 = __builtin_amdgcn_mfma_f32_16x16x32_bf16(a0, b0, acc00, 0,0,0);
    acc01 = __builtin_amdgcn_mfma_f32_16x16x32_bf16(a0, b1, acc01, 0,0,0);
    acc10 = __builtin_amdgcn_mfma_f32_16x16x32_bf16(a1, b0, acc10, 0,0,0);
    acc11 = __builtin_amdgcn_mfma_f32_16x16x32_bf16(a1, b1, acc11, 0,0,0);
  }

  const int mrow = (l>>4)<<2;
  #pragma unroll
  for (int i=0;i<2;i++){
    #pragma unroll
    for (int j=0;j<2;j++){
      const f32x4 av = (i==0) ? (j==0?acc00:acc01) : (j==0?acc10:acc11);
      const int n = n0 + j*16 + lr;
      if (n < E_){
        const unsigned head = (unsigned)n / 162u;
        const int jj = n - (int)head*162;
        const int off = cmp_off(jj);
        #pragma unroll
        for (int reg=0;reg<4;reg++){
          const int m = m0 + i*16 + mrow + reg;
          const int s = m >> 5, bq = m & 31;
          char* rowb = (char*)qc + ((size_t)(bq*8u+head)*S_ + s)*ROWB_;
          *(unsigned short*)(rowb + off) = bfb(av[reg]);
        }
      }
    }
  }
}

// ---------------- GEMM2 (MFMA bf16): out = hs_bf . out_W^T + x ----------------
__global__ __launch_bounds__(256) void gemm2_mfma(const __hip_bfloat16* __restrict__ A,
                                                  const __hip_bfloat16* __restrict__ Bw,
                                                  const float* __restrict__ X,
                                                  float* __restrict__ C){
  const int tid = threadIdx.x;
  const int w = tid >> 6, l = tid & 63;
  const int lr = l & 15, lk = (l >> 4) << 3;
  const int m0 = blockIdx.y*64 + (w>>1)*32;
  const int n0 = blockIdx.x*64 + (w&1)*32;

  const __hip_bfloat16* Ap = A  + (size_t)(m0+lr)*D_ + lk;
  const __hip_bfloat16* Bp = Bw + (size_t)(n0+lr)*D_ + lk;

  f32x4 acc00={0,0,0,0}, acc01={0,0,0,0}, acc10={0,0,0,0}, acc11={0,0,0,0};
  #pragma unroll
  for (int ks = 0; ks < 8; ++ks){
    const bf16x8 a0 = *(const bf16x8*)(Ap + ks*32);
    const bf16x8 a1 = *(const bf16x8*)(Ap + 16*D_ + ks*32);
    const bf16x8 b0 = *(const bf16x8*)(Bp + ks*32);
    const bf16x8 b1 = *(const bf16x8*)(Bp + 16*D_ + ks*32);
    acc00 = __builtin_amdgcn_mfma_f32_16x16x32_bf16(a0, b0, acc00, 0,0,0);
    acc01 = __builtin_amdgcn_mfma_f32_16x16x32_bf16(a0, b1, acc01, 0,0,0);
    acc10 = __builtin_amdgcn_mfma_f32_16x16x32_bf16(a1, b0, acc10, 0,0,0);
    acc11 = __builtin_amdgcn_mfma_f32_16x16x32_bf16(a1, b1, acc11, 0,0,0);
  }

  const int mrow = (l>>4)<<2;
  #pragma unroll
  for (int i=0;i<2;i++){
    #pragma unroll
    for (int j=0;j<2;j++){
      const f32x4 av = (i==0) ? (j==0?acc00:acc01) : (j==0?acc10:acc11);
      const int n = n0 + j*16 + lr;
      #pragma unroll
      for (int reg=0;reg<4;reg++){
        const size_t m = (size_t)(m0 + i*16 + mrow + reg);
        C[m*D_ + n] = av[reg] + X[m*D_ + n];
      }
    }
  }
}

// ---------------- act4: activations in-place on COMPACT bf16 rows ----------------
__global__ __launch_bounds__(256) void act4_kernel(unsigned short* __restrict__ qc){
  const int row = blockIdx.x*8 + (threadIdx.x >> 5);
  const int i = threadIdx.x & 31;
  unsigned short* base = qc + (size_t)row*ROWS_;
  float qv  = bf2f(base[i]);
  float kv  = bf2f(base[32 + i]);
  float rkv = bf2f(base[64 + i]);
  qv = qv > 0.f ? qv + 1.f : __expf(qv);   // elu+1
  kv = kv > 0.f ? kv + 1.f : __expf(kv);
  const float qs = gsum32(qv);
  const float ks = gsum32(kv);
  const float rm = gmax32(rkv);
  const float re = __expf(rkv - rm);
  const float rs = gsum32(re);
  base[i]      = bfb(qv / qs);
  base[32 + i] = bfb(kv / ks);
  base[64 + i] = bfb(re / rs);
  if (i < 2){
    const float bv = bf2f(base[160 + i]);
    base[160 + i] = bfb(1.f/(1.f + __expf(-bv)));
  }
}

// ---------------- fused scan: 2-deep bf16 register pipeline (PROVEN R18) ----------------
// EXACT R18 kernel (366us total, scan 232us, absmax 0.0156). 2-deep
// register double-buffer, inline-asm loads, steady vmcnt(9) (= 8 loads +
// 1 h-store in flight; stores count toward vmcnt on gfx950 — validated).
// DO NOT alter: depth>2, row-grouping, and early-reissue each failed
// (8 total failures: SIGABRT / NaN / wrong values on this toolchain).
#define SCAN_ISSUE(P, sbp)                                                    \
  { const char* sb_ = (sbp);                                                  \
    GL4(P##q0, sb_, voQ, "0");   GL4(P##q1, sb_, voQ, "16");                  \
    GL4(P##k0, sb_, voQ, "64");  GL4(P##k1, sb_, voQ, "80");                  \
    GL4(P##r0, sb_, voQ, "128"); GL4(P##r1, sb_, voQ, "144");                 \
    GL1(P##vr, sb_, voV, "192");                                              \
    GL1(P##bb, sb_, voZ, "320"); }

#define SCAN_BODY(P, tt)                                                      \
  {                                                                           \
    /* e-transpose into the DS pipe first (depends only on prev h) */         \
    const float e_ = __expf(h);                                               \
    ebuf[r] = e_;                                                             \
    f32x4 ev0 = *(const f32x4*)&ebuf[p16+0];                                  \
    f32x4 ev1 = *(const f32x4*)&ebuf[p16+4];                                  \
    f32x4 ev2 = *(const f32x4*)&ebuf[p16+8];                                  \
    f32x4 ev3 = *(const f32x4*)&ebuf[p16+12];                                 \
    /* wait for THIS step's input registers */                                \
    if ((tt) >= S_-2) { asm volatile("s_waitcnt vmcnt(0)" ::: "memory"); }    \
    else              { asm volatile("s_waitcnt vmcnt(9)" ::: "memory"); }    \
    __builtin_amdgcn_sched_barrier(0);                                        \
    /* unpack bf16 (1 VALU op per element) */                                 \
    float q_[16], k_[16], rk_[16];                                            \
    q_[0]=bfl(P##q0[0]);  q_[1]=bfh(P##q0[0]);  q_[2]=bfl(P##q0[1]);  q_[3]=bfh(P##q0[1]); \
    q_[4]=bfl(P##q0[2]);  q_[5]=bfh(P##q0[2]);  q_[6]=bfl(P##q0[3]);  q_[7]=bfh(P##q0[3]); \
    q_[8]=bfl(P##q1[0]);  q_[9]=bfh(P##q1[0]);  q_[10]=bfl(P##q1[1]); q_[11]=bfh(P##q1[1]);\
    q_[12]=bfl(P##q1[2]); q_[13]=bfh(P##q1[2]); q_[14]=bfl(P##q1[3]); q_[15]=bfh(P##q1[3]);\
    k_[0]=bfl(P##k0[0]);  k_[1]=bfh(P##k0[0]);  k_[2]=bfl(P##k0[1]);  k_[3]=bfh(P##k0[1]); \
    k_[4]=bfl(P##k0[2]);  k_[5]=bfh(P##k0[2]);  k_[6]=bfl(P##k0[3]);  k_[7]=bfh(P##k0[3]); \
    k_[8]=bfl(P##k1[0]);  k_[9]=bfh(P##k1[0]);  k_[10]=bfl(P##k1[1]); k_[11]=bfh(P##k1[1]);\
    k_[12]=bfl(P##k1[2]); k_[13]=bfh(P##k1[2]); k_[14]=bfl(P##k1[3]); k_[15]=bfh(P##k1[3]);\
    rk_[0]=bfl(P##r0[0]);  rk_[1]=bfh(P##r0[0]);  rk_[2]=bfl(P##r0[1]);  rk_[3]=bfh(P##r0[1]); \
    rk_[4]=bfl(P##r0[2]);  rk_[5]=bfh(P##r0[2]);  rk_[6]=bfl(P##r0[3]);  rk_[7]=bfh(P##r0[3]); \
    rk_[8]=bfl(P##r1[0]);  rk_[9]=bfh(P##r1[0]);  rk_[10]=bfl(P##r1[1]); rk_[11]=bfh(P##r1[1]);\
    rk_[12]=bfl(P##r1[2]); rk_[13]=bfh(P##r1[2]); rk_[14]=bfl(P##r1[3]); rk_[15]=bfh(P##r1[3]);\
    const float vv   = bfl(P##vr), rvv   = bfh(P##vr);                        \
    const float beta = bfl(P##bb), rbeta = bfh(P##bb);                        \
    /* ---- ff chain ---- */                                                  \
    float a0=0.f,a1=0.f,a2=0.f,a3=0.f;                                        \
    _Pragma("unroll")                                                         \
    for (int c4=0;c4<16;c4+=4){                                               \
      a0=fmaf(W[c4+0],k_[c4+0],a0); a1=fmaf(W[c4+1],k_[c4+1],a1);             \
      a2=fmaf(W[c4+2],k_[c4+2],a2); a3=fmaf(W[c4+3],k_[c4+3],a3);             \
    }                                                                         \
    const float dot1f = xhalf_sum((a0+a1)+(a2+a3));                           \
    const float coeff = beta*(vv - dot1f);                                    \
    float b0=0.f,b1=0.f,b2=0.f,b3=0.f;                                        \
    _Pragma("unroll")                                                         \
    for (int c4=0;c4<16;c4+=4){                                               \
      W[c4+0]=fmaf(coeff,k_[c4+0],W[c4+0]); b0=fmaf(W[c4+0],q_[c4+0],b0);     \
      W[c4+1]=fmaf(coeff,k_[c4+1],W[c4+1]); b1=fmaf(W[c4+1],q_[c4+1],b1);     \
      W[c4+2]=fmaf(coeff,k_[c4+2],W[c4+2]); b2=fmaf(W[c4+2],q_[c4+2],b2);     \
      W[c4+3]=fmaf(coeff,k_[c4+3],W[c4+3]); b3=fmaf(W[c4+3],q_[c4+3],b3);     \
    }                                                                         \
    const float z_ = xhalf_sum((b0+b1)+(b2+b3));                              \
    /* ---- rec R delta update (h-independent) ---- */                        \
    float c0=0.f,c1=0.f,c2=0.f,c3=0.f;                                        \
    _Pragma("unroll")                                                         \
    for (int c4=0;c4<16;c4+=4){                                               \
      c0=fmaf(R[c4+0],rk_[c4+0],c0); c1=fmaf(R[c4+1],rk_[c4+1],c1);           \
      c2=fmaf(R[c4+2],rk_[c4+2],c2); c3=fmaf(R[c4+3],rk_[c4+3],c3);           \
    }                                                                         \
    const float dot1r = xhalf_sum((c0+c1)+(c2+c3));                           \
    const float coefr = rbeta*(rvv - dot1r);                                  \
    _Pragma("unroll")                                                         \
    for (int c4=0;c4<16;c4+=4){                                               \
      R[c4+0]=fmaf(coefr,rk_[c4+0],R[c4+0]); R[c4+1]=fmaf(coefr,rk_[c4+1],R[c4+1]); \
      R[c4+2]=fmaf(coefr,rk_[c4+2],R[c4+2]); R[c4+3]=fmaf(coefr,rk_[c4+3],R[c4+3]); \
    }                                                                         \
    /* ---- softmax-dot from the transposed e (read issued long ago) ---- */  \
    float evv[16];                                                            \
    *(f32x4*)&evv[0]=ev0; *(f32x4*)&evv[4]=ev1;                               \
    *(f32x4*)&evv[8]=ev2; *(f32x4*)&evv[12]=ev3;                              \
    float t0=(evv[0]+evv[1])+(evv[2]+evv[3]),   t1=(evv[4]+evv[5])+(evv[6]+evv[7]); \
    float t2=(evv[8]+evv[9])+(evv[10]+evv[11]), t3=(evv[12]+evv[13])+(evv[14]+evv[15]); \
    const float Ss = xhalf_sum((t0+t1)+(t2+t3));                              \
    float d0=0.f,d1=0.f,d2=0.f,d3=0.f;                                        \
    _Pragma("unroll")                                                         \
    for (int c4=0;c4<16;c4+=4){                                               \
      d0=fmaf(R[c4+0],evv[c4+0],d0); d1=fmaf(R[c4+1],evv[c4+1],d1);           \
      d2=fmaf(R[c4+2],evv[c4+2],d2); d3=fmaf(R[c4+3],evv[c4+3],d3);           \
    }                                                                         \
    const float dot2 = xhalf_sum((d0+d1)+(d2+d3));                            \
    h = fmaf(dot2, __builtin_amdgcn_rcpf(Ss), z_);                            \
    hsb[(size_t)(tt)*(B_*D_) + hoff] = __float2bfloat16(h);                   \
    /* reissue this buffer for step tt+2 */                                   \
    if ((tt)+2 < S_) SCAN_ISSUE(P, gbase + (size_t)((tt)+2)*ROWB_);           \
  }

__global__ __launch_bounds__(64,1) void scan_fused2(const unsigned short* __restrict__ qc,
                                                    __hip_bfloat16* __restrict__ hsb){
  const int pair = blockIdx.x;
  const int lane = threadIdx.x;
  const int r = lane & 31, p = lane >> 5;
  const int p16 = p*16;
  const int b = pair >> 3, hh = pair & 7;
  const char* gbase = (const char*)qc + (size_t)pair*S_*ROWB_;
  const size_t hoff = (size_t)b*D_ + hh*DH_ + r;   // + t*B_*D_ per step

  __shared__ __align__(16) float ebuf[DH_];

  const int voQ = p*32;   // byte voffset for q/k/rk 16-col bf16 slices
  const int voV = r*4;    // byte voffset for the (v,rv) bf16 pair (base 192 in imm)
  const int voZ = 0;      // (beta,rbeta) row-uniform

  float W[16], R[16];
  #pragma unroll
  for (int i=0;i<16;i++){ W[i]=0.f; R[i]=0.f; }
  float h = 0.f;

  // 2-deep register buffer sets A (even steps) / B (odd steps), 26 VGPRs each
  u32x4 Aq0,Aq1, Ak0,Ak1, Ar0,Ar1; unsigned Avr, Abb;
  u32x4 Bq0,Bq1, Bk0,Bk1, Br0,Br1; unsigned Bvr, Bbb;

  SCAN_ISSUE(A, gbase);                 // step 0
  SCAN_ISSUE(B, gbase + ROWB_);         // step 1
  asm volatile("s_waitcnt vmcnt(8)" ::: "memory");   // step-0 regs ready
  __builtin_amdgcn_sched_barrier(0);

  for (int tc = 0; tc < S_; tc += 2){
    SCAN_BODY(A, tc);
    SCAN_BODY(B, tc+1);
  }
}

// ---------------- launcher ----------------
extern "C" void kernel_launch(void* const* d_in, const int* in_sizes, int n_in,
                              void* d_out, int out_size, void* d_ws, size_t ws_size,
                              hipStream_t stream) {
  const float* x      = (const float*)d_in[0];
  const float* slow_W = (const float*)d_in[1];
  const float* out_W  = (const float*)d_in[2];
  const float* ln_g   = (const float*)d_in[3];
  const float* ln_b   = (const float*)d_in[4];
  float* out = (float*)d_out;

  // ws layout: qc (compact bf16) 50.3MB | obf/hsb (overlaid) 8.4MB | w1 | w2
  unsigned short* qc  = (unsigned short*)d_ws;                  // [256][512][192 ushorts]
  __hip_bfloat16* obf = (__hip_bfloat16*)((char*)d_ws + (size_t)B_*H_*S_*ROWB_);
  __hip_bfloat16* hsb = obf;                                    // overlay: obf dead after gemm1
  __hip_bfloat16* w1bf = obf + (size_t)SB_*D_;                  // [1344][256]
  __hip_bfloat16* w2bf = w1bf + (size_t)NPAD_*D_;               // [256][256]

  cvt_w<<<NPAD_ + D_, 256, 0, stream>>>(slow_W, out_W, w1bf, w2bf);
  ln_kernel<<<SB_, 256, 0, stream>>>(x, ln_g, ln_b, obf);

  dim3 g1(NPAD_/64, SB_/64);                   // (21, 256)
  gemm1_mfma<<<g1, 256, 0, stream>>>(obf, w1bf, qc);

  act4_kernel<<<B_*H_*S_/8, 256, 0, stream>>>(qc);

  scan_fused2<<<B_*H_, 64, 0, stream>>>(qc, hsb);

  dim3 g2(D_/64, SB_/64);                      // (4, 256)
  gemm2_mfma<<<g2, 256, 0, stream>>>(hsb, w2bf, x, out);
}